// Round 5
// baseline (170.224 us; speedup 1.0000x reference)
//
#include <hip/hip_runtime.h>
#include <hip/hip_bf16.h>
#include <cstdint>

typedef __attribute__((ext_vector_type(8))) short short8;
typedef __attribute__((ext_vector_type(4))) float floatx4;
typedef __attribute__((ext_vector_type(4))) float fx4;   // native vec for nontemporal builtins

#define ROWS 64       // samples per block
#define NTHREADS 256  // 4 waves: wave w owns out-channels [64w, 64w+64) x all 64 samples
#define RSTRIDE 296   // ushorts/row: 256 act + 24 PE + 8 zero + 8 pad; word-stride 148 = 20 mod 32

// raw barriers: LDS-only protection, keep global loads in flight (no vmcnt drain)
#define BAR_PLAIN asm volatile("s_barrier" ::: "memory")
#define BAR_LGKM  asm volatile("s_waitcnt lgkmcnt(0)\n\ts_barrier" ::: "memory")

__device__ __forceinline__ ushort f2bf(float x) {
  union { float f; uint32_t u; } v; v.f = x;
  uint32_t r = v.u + 0x7fffu + ((v.u >> 16) & 1u);  // RNE
  return (ushort)(r >> 16);
}

__device__ __forceinline__ uint32_t cvtpk2(float lo, float hi) {
  uint32_t r;
  asm("v_cvt_pk_bf16_f32 %0, %1, %2" : "=v"(r) : "v"(lo), "v"(hi));
  return r;
}

// ---------------- prep: transpose weights to bf16 [out][in] ----------------
__global__ void prep_kernel(const float* __restrict__ W1a, const float* __restrict__ W1b,
                            const float* __restrict__ W3a, const float* __restrict__ W3b,
                            const float* __restrict__ Wa,  const float* __restrict__ Wc,
                            const float* __restrict__ ba,  const float* __restrict__ bc,
                            ushort* __restrict__ W1aT, ushort* __restrict__ W1bT,
                            ushort* __restrict__ W3aT, ushort* __restrict__ W3bT,
                            ushort* __restrict__ whead, float* __restrict__ hbias)
{
  int b = blockIdx.x, t = threadIdx.x;
  // [256][256] mats: in[k=b][n=t] -> out[n][k]
  W1bT[t * 256 + b] = f2bf(W1b[b * 256 + t]);
  W3aT[t * 256 + b] = f2bf(W3a[b * 256 + t]);
  W3bT[t * 256 + b] = f2bf(W3b[b * 256 + t]);
  if (b < 32) W1aT[t * 32 + b] = f2bf(W1a[b * 256 + t]);
  if (b == 255) {
    // head matrix [16][288]: row0 = Wa (K=256, PE cols zero), rows 1..3 = Wc^T (K=280), rows 4..15 zero
    for (int k = t; k < 288; k += 256) {
      for (int r = 0; r < 16; ++r) {
        float v = 0.f;
        if (r == 0)     v = (k < 256) ? Wa[k] : 0.f;
        else if (r < 4) v = (k < 280) ? Wc[k * 3 + (r - 1)] : 0.f;
        whead[r * 288 + k] = f2bf(v);
      }
    }
    if (t == 0) { hbias[0] = ba[0]; hbias[1] = bc[0]; hbias[2] = bc[1]; hbias[3] = bc[2]; }
  }
}

// one in-place MLP layer: buf stores [sample][channel]; D[outch][samp] = W^T . X^T
// Wave owns 64 out-channels (mbase) x all 64 samples.
template<int NKT, int KST>
__device__ __forceinline__ void mlp_layer(ushort (*buf)[RSTRIDE],
                                          const ushort* __restrict__ WT,
                                          const float* __restrict__ bias,
                                          int mbase, int lrow, int kgrp)
{
  floatx4 acc[4][4] = {};
  __builtin_amdgcn_s_setprio(1);
  #pragma unroll
  for (int kt = 0; kt < NKT; ++kt) {
    short8 a[4], b[4];
    #pragma unroll
    for (int mt = 0; mt < 4; ++mt)
      a[mt] = *(const short8*)&WT[(size_t)(mbase + mt * 16 + lrow) * KST + kt * 32 + kgrp * 8];
    #pragma unroll
    for (int nt = 0; nt < 4; ++nt)
      b[nt] = *(const short8*)&buf[nt * 16 + lrow][kt * 32 + kgrp * 8];
    #pragma unroll
    for (int mt = 0; mt < 4; ++mt)
      #pragma unroll
      for (int nt = 0; nt < 4; ++nt)
        acc[mt][nt] = __builtin_amdgcn_mfma_f32_16x16x32_bf16(a[mt], b[nt], acc[mt][nt], 0, 0, 0);
  }
  __builtin_amdgcn_s_setprio(0);
  BAR_PLAIN;   // all waves' reads of buf are complete (consumed by their MFMAs)
  #pragma unroll
  for (int mt = 0; mt < 4; ++mt) {
    float4 bv = *(const float4*)(bias + mbase + mt * 16 + kgrp * 4);
    #pragma unroll
    for (int nt = 0; nt < 4; ++nt) {
      uint2 pk;
      pk.x = cvtpk2(fmaxf(acc[mt][nt][0] + bv.x, 0.f), fmaxf(acc[mt][nt][1] + bv.y, 0.f));
      pk.y = cvtpk2(fmaxf(acc[mt][nt][2] + bv.z, 0.f), fmaxf(acc[mt][nt][3] + bv.w, 0.f));
      *(uint2*)&buf[nt * 16 + lrow][mbase + mt * 16 + kgrp * 4] = pk;
    }
  }
  BAR_LGKM;    // writes visible before next layer's reads
}

// ---------------- fused: aggregate + 4-layer MLP + MFMA head ----------------
__global__ __launch_bounds__(NTHREADS, 4) void pa_fused(
    const float* __restrict__ emb, const float* __restrict__ dists,
    const float* __restrict__ viewdirs, const int* __restrict__ pnt_mask,
    const ushort* __restrict__ W1aT, const float* __restrict__ b1a,
    const ushort* __restrict__ W1bT, const float* __restrict__ b1b,
    const ushort* __restrict__ W3aT, const float* __restrict__ b3a,
    const ushort* __restrict__ W3bT, const float* __restrict__ b3b,
    const ushort* __restrict__ whead, const float* __restrict__ hbias,
    float* __restrict__ out)
{
  __shared__ ushort buf[ROWS][RSTRIDE];
  const int tid  = threadIdx.x;
  const int base = blockIdx.x * ROWS;

  // --- Phase A: weights (redundant x4) + feat + viewdir PE, no internal barrier ---
  {
    const int s = tid >> 2, g = tid & 3;
    const int gs = base + s;
    float d[24];
    const float4* d4 = (const float4*)(dists + (size_t)gs * 24);
    #pragma unroll
    for (int i = 0; i < 6; ++i) {
      float4 q = d4[i];
      d[4*i] = q.x; d[4*i+1] = q.y; d[4*i+2] = q.z; d[4*i+3] = q.w;
    }
    const int4* m4 = (const int4*)(pnt_mask + (size_t)gs * 8);
    int4 m0 = m4[0], m1 = m4[1];
    int mk[8] = {m0.x, m0.y, m0.z, m0.w, m1.x, m1.y, m1.z, m1.w};
    float wv[8]; float sum = 0.f;
    #pragma unroll
    for (int k = 0; k < 8; ++k) {
      float d2 = d[3*k]*d[3*k] + d[3*k+1]*d[3*k+1] + d[3*k+2]*d[3*k+2];
      wv[k] = (float)mk[k] * __builtin_amdgcn_rcpf(fmaxf(d2, 1e-8f));
      sum += wv[k];
    }
    float inv = __builtin_amdgcn_rcpf(fmaxf(sum, 1e-8f));
    #pragma unroll
    for (int k = 0; k < 8; ++k) wv[k] *= inv;

    // feat: this thread covers features g*8 .. g*8+7 (emb is the big stream -> NT loads)
    float acc[8] = {0.f, 0.f, 0.f, 0.f, 0.f, 0.f, 0.f, 0.f};
    #pragma unroll
    for (int k = 0; k < 8; ++k) {
      const fx4* e4 = (const fx4*)(emb + ((size_t)(gs * 8 + k)) * 32 + g * 8);
      fx4 e0 = __builtin_nontemporal_load(e4);
      fx4 e1 = __builtin_nontemporal_load(e4 + 1);
      acc[0] += wv[k]*e0.x; acc[1] += wv[k]*e0.y; acc[2] += wv[k]*e0.z; acc[3] += wv[k]*e0.w;
      acc[4] += wv[k]*e1.x; acc[5] += wv[k]*e1.y; acc[6] += wv[k]*e1.z; acc[7] += wv[k]*e1.w;
    }
    uint4 fp;
    fp.x = cvtpk2(acc[0], acc[1]); fp.y = cvtpk2(acc[2], acc[3]);
    fp.z = cvtpk2(acc[4], acc[5]); fp.w = cvtpk2(acc[6], acc[7]);
    *(uint4*)&buf[s][g * 8] = fp;

    // viewdir PE: this thread handles freq f = g -> cols 256 + 6g .. 256 + 6g + 5
    float vx = viewdirs[(size_t)gs * 3 + 0];
    float vy = viewdirs[(size_t)gs * 3 + 1];
    float vz = viewdirs[(size_t)gs * 3 + 2];
    float nrm = sqrtf(vx*vx + vy*vy + vz*vz);
    float ninv = __builtin_amdgcn_rcpf(fmaxf(nrm, 1e-8f));
    float fr = (float)(1 << g) * ninv;
    float sx, cx, sy, cy, sz, cz;
    sincosf(vx * fr, &sx, &cx);
    sincosf(vy * fr, &sy, &cy);
    sincosf(vz * fr, &sz, &cz);
    uint32_t* pe = (uint32_t*)&buf[s][256 + g * 6];
    pe[0] = cvtpk2(sx, sy);
    pe[1] = cvtpk2(sz, cx);
    pe[2] = cvtpk2(cy, cz);
    if (g == 3) {                       // zero cols 280..287 (K padding for head)
      uint4 z = {0, 0, 0, 0};
      *(uint4*)&buf[s][280] = z;
    }
  }
  BAR_LGKM;

  const int lane = tid & 63;
  const int wid  = tid >> 6;
  const int lrow = lane & 15;
  const int kgrp = lane >> 4;
  const int mbase = wid * 64;          // out-channel chunk; samples = all 64

  mlp_layer<1, 32>(buf, W1aT, b1a, mbase, lrow, kgrp);
  mlp_layer<8, 256>(buf, W1bT, b1b, mbase, lrow, kgrp);
  mlp_layer<8, 256>(buf, W3aT, b3a, mbase, lrow, kgrp);
  mlp_layer<8, 256>(buf, W3bT, b3b, mbase, lrow, kgrp);

  // --- Head via MFMA: [16 x 288] . [288 x 16 samples], wave w owns samples 16w..16w+15 ---
  {
    floatx4 hacc = {0.f, 0.f, 0.f, 0.f};
    #pragma unroll
    for (int kt = 0; kt < 9; ++kt) {
      short8 a = *(const short8*)&whead[(size_t)lrow * 288 + kt * 32 + kgrp * 8];
      short8 b = *(const short8*)&buf[wid * 16 + lrow][kt * 32 + kgrp * 8];
      hacc = __builtin_amdgcn_mfma_f32_16x16x32_bf16(a, b, hacc, 0, 0, 0);
    }
    // C layout: sample = lane&15, outch = (lane>>4)*4 + r -> lanes 0..15 hold ch 0..3
    if (lane < 16) {
      float4 hb = *(const float4*)hbias;
      float ra = hacc[0] + hb.x - 1.f;                         // softplus(x-1)
      float alpha = fmaxf(ra, 0.f) + log1pf(expf(-fabsf(ra)));
      float c0 = hacc[1] + hb.y, c1 = hacc[2] + hb.z, c2 = hacc[3] + hb.w;
      fx4 o;
      o.x = alpha;
      o.y = 1.f / (1.f + expf(-c0)) * 1.002f - 1e-3f;
      o.z = 1.f / (1.f + expf(-c1)) * 1.002f - 1e-3f;
      o.w = 1.f / (1.f + expf(-c2)) * 1.002f - 1e-3f;
      int gs = base + wid * 16 + lane;
      __builtin_nontemporal_store(o, (fx4*)(out + (size_t)gs * 4));
    }
  }
}

extern "C" void kernel_launch(void* const* d_in, const int* in_sizes, int n_in,
                              void* d_out, int out_size, void* d_ws, size_t ws_size,
                              hipStream_t stream)
{
  const float* emb   = (const float*)d_in[0];
  const float* dists = (const float*)d_in[1];
  const float* vdirs = (const float*)d_in[2];
  const int*   mask  = (const int*)d_in[3];
  const float* W1a = (const float*)d_in[4];
  const float* b1a = (const float*)d_in[5];
  const float* W1b = (const float*)d_in[6];
  const float* b1b = (const float*)d_in[7];
  const float* W3a = (const float*)d_in[8];
  const float* b3a = (const float*)d_in[9];
  const float* W3b = (const float*)d_in[10];
  const float* b3b = (const float*)d_in[11];
  const float* Wa  = (const float*)d_in[12];
  const float* ba  = (const float*)d_in[13];
  const float* Wc  = (const float*)d_in[14];
  const float* bc  = (const float*)d_in[15];

  // workspace layout: bf16 mats then head mat then f32 bias
  ushort* wsb  = (ushort*)d_ws;
  ushort* W1aT  = wsb;             // 256*32
  ushort* W1bT  = wsb + 8192;      // 256*256
  ushort* W3aT  = wsb + 73728;     // 256*256
  ushort* W3bT  = wsb + 139264;    // 256*256
  ushort* whead = wsb + 204800;    // 16*288
  float*  hbias = (float*)(wsb + 209408);  // 4 floats

  prep_kernel<<<256, 256, 0, stream>>>(W1a, W1b, W3a, W3b, Wa, Wc, ba, bc,
                                       W1aT, W1bT, W3aT, W3bT, whead, hbias);

  int nsamples = in_sizes[2] / 3;        // B*R*SR = 163840
  int nblocks  = nsamples / ROWS;        // 2560
  pa_fused<<<nblocks, NTHREADS, 0, stream>>>(emb, dists, vdirs, mask,
                                             W1aT, b1a, W1bT, b1b, W3aT, b3a, W3bT, b3b,
                                             whead, hbias, (float*)d_out);
}

// Round 6
// 129.716 us; speedup vs baseline: 1.3123x; 1.3123x over previous
//
#include <hip/hip_runtime.h>
#include <hip/hip_bf16.h>
#include <cstdint>

typedef __attribute__((ext_vector_type(8))) short short8;
typedef __attribute__((ext_vector_type(4))) float floatx4;
typedef __attribute__((ext_vector_type(4))) float fx4;   // native vec for nontemporal builtins

#define ROWS 128      // samples per block
#define NTHREADS 256  // 4 waves: wave w owns out-channels [64w,64w+64) x ALL 128 samples
#define RSTRIDE 296   // ushorts/row: 256 act + 24 PE + 8 zero + 8 pad; 592B row = 37 quads (odd)

// raw barriers: LDS-only protection, keep global loads in flight (no vmcnt drain)
#define BAR_PLAIN asm volatile("s_barrier" ::: "memory")
#define BAR_LGKM  asm volatile("s_waitcnt lgkmcnt(0)\n\ts_barrier" ::: "memory")

__device__ __forceinline__ ushort f2bf(float x) {
  union { float f; uint32_t u; } v; v.f = x;
  uint32_t r = v.u + 0x7fffu + ((v.u >> 16) & 1u);  // RNE
  return (ushort)(r >> 16);
}

__device__ __forceinline__ uint32_t cvtpk2(float lo, float hi) {
  uint32_t r;
  asm("v_cvt_pk_bf16_f32 %0, %1, %2" : "=v"(r) : "v"(lo), "v"(hi));
  return r;
}

// ---------------- prep: transpose weights to bf16 [out][in] ----------------
__global__ void prep_kernel(const float* __restrict__ W1a, const float* __restrict__ W1b,
                            const float* __restrict__ W3a, const float* __restrict__ W3b,
                            const float* __restrict__ Wa,  const float* __restrict__ Wc,
                            const float* __restrict__ ba,  const float* __restrict__ bc,
                            ushort* __restrict__ W1aT, ushort* __restrict__ W1bT,
                            ushort* __restrict__ W3aT, ushort* __restrict__ W3bT,
                            ushort* __restrict__ whead, float* __restrict__ hbias)
{
  int b = blockIdx.x, t = threadIdx.x;
  // [256][256] mats: in[k=b][n=t] -> out[n][k]
  W1bT[t * 256 + b] = f2bf(W1b[b * 256 + t]);
  W3aT[t * 256 + b] = f2bf(W3a[b * 256 + t]);
  W3bT[t * 256 + b] = f2bf(W3b[b * 256 + t]);
  if (b < 32) W1aT[t * 32 + b] = f2bf(W1a[b * 256 + t]);
  if (b == 255) {
    // head matrix [16][288]: row0 = Wa (K=256, PE cols zero), rows 1..3 = Wc^T (K=280), rows 4..15 zero
    for (int k = t; k < 288; k += 256) {
      for (int r = 0; r < 16; ++r) {
        float v = 0.f;
        if (r == 0)     v = (k < 256) ? Wa[k] : 0.f;
        else if (r < 4) v = (k < 280) ? Wc[k * 3 + (r - 1)] : 0.f;
        whead[r * 288 + k] = f2bf(v);
      }
    }
    if (t == 0) { hbias[0] = ba[0]; hbias[1] = bc[0]; hbias[2] = bc[1]; hbias[3] = bc[2]; }
  }
}

// one in-place MLP layer: buf stores [sample][channel]; D[outch][samp] = W^T . X^T
// Wave owns 64 out-channels (mbase) x all 128 samples. Explicit next-kt weight prefetch.
template<int NKT, int KST>
__device__ __forceinline__ void mlp_layer(ushort (*buf)[RSTRIDE],
                                          const ushort* __restrict__ WT,
                                          const float* __restrict__ bias,
                                          int mbase, int lrow, int kgrp)
{
  floatx4 acc[4][8] = {};
  short8 a[4];
  #pragma unroll
  for (int mt = 0; mt < 4; ++mt)
    a[mt] = *(const short8*)&WT[(size_t)(mbase + mt * 16 + lrow) * KST + kgrp * 8];
  __builtin_amdgcn_s_setprio(1);
  #pragma unroll
  for (int kt = 0; kt < NKT; ++kt) {
    short8 an[4];
    if (kt + 1 < NKT) {
      #pragma unroll
      for (int mt = 0; mt < 4; ++mt)
        an[mt] = *(const short8*)&WT[(size_t)(mbase + mt * 16 + lrow) * KST
                                     + (kt + 1) * 32 + kgrp * 8];
    }
    short8 b[8];
    #pragma unroll
    for (int nt = 0; nt < 8; ++nt)
      b[nt] = *(const short8*)&buf[nt * 16 + lrow][kt * 32 + kgrp * 8];
    #pragma unroll
    for (int mt = 0; mt < 4; ++mt)
      #pragma unroll
      for (int nt = 0; nt < 8; ++nt)
        acc[mt][nt] = __builtin_amdgcn_mfma_f32_16x16x32_bf16(a[mt], b[nt], acc[mt][nt], 0, 0, 0);
    if (kt + 1 < NKT) {
      #pragma unroll
      for (int mt = 0; mt < 4; ++mt) a[mt] = an[mt];
    }
  }
  __builtin_amdgcn_s_setprio(0);
  BAR_PLAIN;   // all waves' LDS reads complete before in-place overwrite
  #pragma unroll
  for (int mt = 0; mt < 4; ++mt) {
    float4 bv = *(const float4*)(bias + mbase + mt * 16 + kgrp * 4);
    #pragma unroll
    for (int nt = 0; nt < 8; ++nt) {
      uint2 pk;
      pk.x = cvtpk2(fmaxf(acc[mt][nt][0] + bv.x, 0.f), fmaxf(acc[mt][nt][1] + bv.y, 0.f));
      pk.y = cvtpk2(fmaxf(acc[mt][nt][2] + bv.z, 0.f), fmaxf(acc[mt][nt][3] + bv.w, 0.f));
      *(uint2*)&buf[nt * 16 + lrow][mbase + mt * 16 + kgrp * 4] = pk;
    }
  }
  BAR_LGKM;    // writes visible before next layer's reads
}

// ---------------- fused: aggregate + 4-layer MLP + MFMA head ----------------
__global__ __launch_bounds__(NTHREADS, 2) void pa_fused(
    const float* __restrict__ emb, const float* __restrict__ dists,
    const float* __restrict__ viewdirs, const int* __restrict__ pnt_mask,
    const ushort* __restrict__ W1aT, const float* __restrict__ b1a,
    const ushort* __restrict__ W1bT, const float* __restrict__ b1b,
    const ushort* __restrict__ W3aT, const float* __restrict__ b3a,
    const ushort* __restrict__ W3bT, const float* __restrict__ b3b,
    const ushort* __restrict__ whead, const float* __restrict__ hbias,
    float* __restrict__ out)
{
  __shared__ ushort buf[ROWS][RSTRIDE];
  const int tid  = threadIdx.x;
  const int base = blockIdx.x * ROWS;

  // --- Phase A: weights (redundant x2) + feat (16 ch/thread) + viewdir PE (2 freq/thread) ---
  {
    const int s = tid >> 1, g = tid & 1;
    const int gs = base + s;
    float d[24];
    const float4* d4 = (const float4*)(dists + (size_t)gs * 24);
    #pragma unroll
    for (int i = 0; i < 6; ++i) {
      float4 q = d4[i];
      d[4*i] = q.x; d[4*i+1] = q.y; d[4*i+2] = q.z; d[4*i+3] = q.w;
    }
    const int4* m4 = (const int4*)(pnt_mask + (size_t)gs * 8);
    int4 m0 = m4[0], m1 = m4[1];
    int mk[8] = {m0.x, m0.y, m0.z, m0.w, m1.x, m1.y, m1.z, m1.w};
    float wv[8]; float sum = 0.f;
    #pragma unroll
    for (int k = 0; k < 8; ++k) {
      float d2 = d[3*k]*d[3*k] + d[3*k+1]*d[3*k+1] + d[3*k+2]*d[3*k+2];
      wv[k] = (float)mk[k] * __builtin_amdgcn_rcpf(fmaxf(d2, 1e-8f));
      sum += wv[k];
    }
    float inv = __builtin_amdgcn_rcpf(fmaxf(sum, 1e-8f));
    #pragma unroll
    for (int k = 0; k < 8; ++k) wv[k] *= inv;

    // feat: this thread covers features g*16 .. g*16+15 (emb is the big stream -> NT loads)
    float acc[16];
    #pragma unroll
    for (int j = 0; j < 16; ++j) acc[j] = 0.f;
    #pragma unroll
    for (int k = 0; k < 8; ++k) {
      const fx4* e4 = (const fx4*)(emb + ((size_t)(gs * 8 + k)) * 32 + g * 16);
      fx4 e0 = __builtin_nontemporal_load(e4);
      fx4 e1 = __builtin_nontemporal_load(e4 + 1);
      fx4 e2 = __builtin_nontemporal_load(e4 + 2);
      fx4 e3 = __builtin_nontemporal_load(e4 + 3);
      acc[0]  += wv[k]*e0.x; acc[1]  += wv[k]*e0.y; acc[2]  += wv[k]*e0.z; acc[3]  += wv[k]*e0.w;
      acc[4]  += wv[k]*e1.x; acc[5]  += wv[k]*e1.y; acc[6]  += wv[k]*e1.z; acc[7]  += wv[k]*e1.w;
      acc[8]  += wv[k]*e2.x; acc[9]  += wv[k]*e2.y; acc[10] += wv[k]*e2.z; acc[11] += wv[k]*e2.w;
      acc[12] += wv[k]*e3.x; acc[13] += wv[k]*e3.y; acc[14] += wv[k]*e3.z; acc[15] += wv[k]*e3.w;
    }
    uint4 fp0, fp1;
    fp0.x = cvtpk2(acc[0],  acc[1]);  fp0.y = cvtpk2(acc[2],  acc[3]);
    fp0.z = cvtpk2(acc[4],  acc[5]);  fp0.w = cvtpk2(acc[6],  acc[7]);
    fp1.x = cvtpk2(acc[8],  acc[9]);  fp1.y = cvtpk2(acc[10], acc[11]);
    fp1.z = cvtpk2(acc[12], acc[13]); fp1.w = cvtpk2(acc[14], acc[15]);
    *(uint4*)&buf[s][g * 16]     = fp0;
    *(uint4*)&buf[s][g * 16 + 8] = fp1;

    // viewdir PE: thread g handles freqs {2g, 2g+1} -> cols 256+12g .. 256+12g+11
    float vx = viewdirs[(size_t)gs * 3 + 0];
    float vy = viewdirs[(size_t)gs * 3 + 1];
    float vz = viewdirs[(size_t)gs * 3 + 2];
    float nrm = sqrtf(vx*vx + vy*vy + vz*vz);
    float ninv = __builtin_amdgcn_rcpf(fmaxf(nrm, 1e-8f));
    uint32_t* pe = (uint32_t*)&buf[s][256 + g * 12];
    #pragma unroll
    for (int h = 0; h < 2; ++h) {
      float fr = (float)(1 << (2 * g + h)) * ninv;
      float sx, cx, sy, cy, sz, cz;
      sincosf(vx * fr, &sx, &cx);
      sincosf(vy * fr, &sy, &cy);
      sincosf(vz * fr, &sz, &cz);
      pe[3*h + 0] = cvtpk2(sx, sy);
      pe[3*h + 1] = cvtpk2(sz, cx);
      pe[3*h + 2] = cvtpk2(cy, cz);
    }
    if (g == 1) {                       // zero cols 280..287 (K padding for head)
      uint4 z = {0, 0, 0, 0};
      *(uint4*)&buf[s][280] = z;
    }
  }
  BAR_LGKM;

  const int lane = tid & 63;
  const int wid  = tid >> 6;
  const int lrow = lane & 15;
  const int kgrp = lane >> 4;
  const int mbase = wid * 64;          // out-channel chunk; samples = all 128

  mlp_layer<1, 32>(buf, W1aT, b1a, mbase, lrow, kgrp);
  mlp_layer<8, 256>(buf, W1bT, b1b, mbase, lrow, kgrp);
  mlp_layer<8, 256>(buf, W3aT, b3a, mbase, lrow, kgrp);
  mlp_layer<8, 256>(buf, W3bT, b3b, mbase, lrow, kgrp);

  // --- Head via MFMA: [16 x 288] . [288 x 16 samples], wave w owns samples 32w..32w+31 ---
  #pragma unroll
  for (int h = 0; h < 2; ++h) {
    floatx4 hacc = {0.f, 0.f, 0.f, 0.f};
    #pragma unroll
    for (int kt = 0; kt < 9; ++kt) {
      short8 a = *(const short8*)&whead[(size_t)lrow * 288 + kt * 32 + kgrp * 8];
      short8 b = *(const short8*)&buf[wid * 32 + h * 16 + lrow][kt * 32 + kgrp * 8];
      hacc = __builtin_amdgcn_mfma_f32_16x16x32_bf16(a, b, hacc, 0, 0, 0);
    }
    // C layout: sample = lane&15, outch = (lane>>4)*4 + r -> lanes 0..15 hold ch 0..3
    if (lane < 16) {
      float4 hb = *(const float4*)hbias;
      float ra = hacc[0] + hb.x - 1.f;                         // softplus(x-1)
      float alpha = fmaxf(ra, 0.f) + log1pf(expf(-fabsf(ra)));
      float c0 = hacc[1] + hb.y, c1 = hacc[2] + hb.z, c2 = hacc[3] + hb.w;
      fx4 o;
      o.x = alpha;
      o.y = 1.f / (1.f + expf(-c0)) * 1.002f - 1e-3f;
      o.z = 1.f / (1.f + expf(-c1)) * 1.002f - 1e-3f;
      o.w = 1.f / (1.f + expf(-c2)) * 1.002f - 1e-3f;
      int gs = base + wid * 32 + h * 16 + lane;
      __builtin_nontemporal_store(o, (fx4*)(out + (size_t)gs * 4));
    }
  }
}

extern "C" void kernel_launch(void* const* d_in, const int* in_sizes, int n_in,
                              void* d_out, int out_size, void* d_ws, size_t ws_size,
                              hipStream_t stream)
{
  const float* emb   = (const float*)d_in[0];
  const float* dists = (const float*)d_in[1];
  const float* vdirs = (const float*)d_in[2];
  const int*   mask  = (const int*)d_in[3];
  const float* W1a = (const float*)d_in[4];
  const float* b1a = (const float*)d_in[5];
  const float* W1b = (const float*)d_in[6];
  const float* b1b = (const float*)d_in[7];
  const float* W3a = (const float*)d_in[8];
  const float* b3a = (const float*)d_in[9];
  const float* W3b = (const float*)d_in[10];
  const float* b3b = (const float*)d_in[11];
  const float* Wa  = (const float*)d_in[12];
  const float* ba  = (const float*)d_in[13];
  const float* Wc  = (const float*)d_in[14];
  const float* bc  = (const float*)d_in[15];

  // workspace layout: bf16 mats then head mat then f32 bias
  ushort* wsb  = (ushort*)d_ws;
  ushort* W1aT  = wsb;             // 256*32
  ushort* W1bT  = wsb + 8192;      // 256*256
  ushort* W3aT  = wsb + 73728;     // 256*256
  ushort* W3bT  = wsb + 139264;    // 256*256
  ushort* whead = wsb + 204800;    // 16*288
  float*  hbias = (float*)(wsb + 209408);  // 4 floats

  prep_kernel<<<256, 256, 0, stream>>>(W1a, W1b, W3a, W3b, Wa, Wc, ba, bc,
                                       W1aT, W1bT, W3aT, W3bT, whead, hbias);

  int nsamples = in_sizes[2] / 3;        // B*R*SR = 163840
  int nblocks  = nsamples / ROWS;        // 1280
  pa_fused<<<nblocks, NTHREADS, 0, stream>>>(emb, dists, vdirs, mask,
                                             W1aT, b1a, W1bT, b1b, W3aT, b3a, W3bT, b3b,
                                             whead, hbias, (float*)d_out);
}